// Round 1
// baseline (5893.986 us; speedup 1.0000x reference)
//
#include <hip/hip_runtime.h>
#include <hip/hip_bf16.h>
#include <stdint.h>

#define TT 1024
#define BB 4
#define HH 512
#define PP 20
#define VV 32000
#define G4 2048
#define GP 80
#define POISON 0xAAAAAAAAu

typedef __bf16 bf16x8 __attribute__((ext_vector_type(8)));
typedef float f32x4 __attribute__((ext_vector_type(4)));

__device__ __forceinline__ float bfu(unsigned short u){ return __uint_as_float(((uint32_t)u)<<16); }
__device__ __forceinline__ uint32_t f2bf_bits(float f){
  uint32_t u = __float_as_uint(f);
  return (u + 0x7FFFu + ((u>>16)&1u)) >> 16;
}
// fast, saturation-safe sigmoid/tanh (v_exp_f32 + v_rcp_f32, ~2 ulp)
__device__ __forceinline__ float fsigm(float x){
  return __builtin_amdgcn_rcpf(1.0f + __expf(-x));
}
__device__ __forceinline__ float ftanh(float x){
  // 1 - 2/(e^{2x}+1): x->+inf: rcp(inf)=0 -> 1; x->-inf: rcp(1)=1 -> -1
  return 1.0f - 2.0f*__builtin_amdgcn_rcpf(__expf(2.0f*x) + 1.0f);
}

__device__ __forceinline__ void gload_lds16(const void* g, void* l){
  __builtin_amdgcn_global_load_lds((__attribute__((address_space(1))) void*)(g),
                                   (__attribute__((address_space(3))) void*)(l), 16, 0, 0);
}

// ---------------- K0: detect input float width (bf16 vs f32) --------------------------
__global__ void k0_detect(const unsigned short* __restrict__ emb_raw, uint32_t* __restrict__ flag){
  __shared__ int cnt;
  if (threadIdx.x==0) cnt = 0;
  __syncthreads();
  int c = 0;
  for (int i=threadIdx.x; i<8192; i+=256){
    float f = bfu(emb_raw[i]);
    if (fabsf(f) >= 0.25f) c++;
  }
  atomicAdd(&cnt, c);
  __syncthreads();
  if (threadIdx.x==0) *flag = (cnt > 64) ? 1u : 0u;   // 1 = f32 inputs
}

// ---------------- KC: canonicalize float inputs -> bf16 and/or f32 copies -------------
struct CvtDesc { const void* src; unsigned short* dbf; float* df32; int n; };
struct CvtTab  { CvtDesc d[16]; };

__global__ __launch_bounds__(256) void kC_convert(CvtTab tab, const uint32_t* __restrict__ flag){
  const uint32_t md = *flag;
  const CvtDesc de = tab.d[blockIdx.y];
  const int stride = gridDim.x * 256;
  for (int i = blockIdx.x*256 + threadIdx.x; i < de.n; i += stride){
    float v;
    if (md) v = ((const float*)de.src)[i];
    else    v = bfu(((const unsigned short*)de.src)[i]);
    if (de.dbf)  de.dbf[i]  = (unsigned short)f2bf_bits(v);
    if (de.df32) de.df32[i] = v;
  }
}

// ---------------- K1: x = emb[ids]; xw = x @ Wih^T + (bih + bhh) (bf16 MFMA) ----------
// out layout: xw[t][b][2048] fp32.  bhh folded in so the recurrent loop skips it.
__global__ __launch_bounds__(256) void k1_embed_xw(
    const int* __restrict__ ids, const unsigned short* __restrict__ emb,
    const unsigned short* __restrict__ Wih, const float* __restrict__ bih,
    const float* __restrict__ bhh, float* __restrict__ xw)
{
  __shared__ __align__(16) unsigned short tA[128*64];
  __shared__ __align__(16) unsigned short tB[128*64];
  const int tid = threadIdx.x, lane = tid & 63, wid = tid >> 6;
  const int wm = wid >> 1, wn = wid & 1;
  const int m0 = blockIdx.x*128, n0 = blockIdx.y*128;
  const int srow = wid*8 + (lane>>3), skc = lane & 7;
  const int quad = lane >> 4, r16 = lane & 15;

  int aid[4];
  #pragma unroll
  for (int q=0;q<4;q++) aid[q] = ids[m0 + q*32 + srow];

  f32x4 acc[4][4];
  #pragma unroll
  for (int i=0;i<4;i++)
    #pragma unroll
    for (int j=0;j<4;j++) acc[i][j] = (f32x4){0.f,0.f,0.f,0.f};

  for (int k0=0;k0<HH;k0+=64){
    #pragma unroll
    for (int q=0;q<4;q++){
      gload_lds16(emb + (size_t)aid[q]*HH + k0 + skc*8, (char*)tA + q*4096 + wid*1024);
      gload_lds16(Wih + (size_t)(n0 + q*32 + srow)*HH + k0 + skc*8, (char*)tB + q*4096 + wid*1024);
    }
    __builtin_amdgcn_s_waitcnt(0);
    __syncthreads();
    #pragma unroll
    for (int kk=0;kk<2;kk++){
      bf16x8 af[4], bfr[4];
      #pragma unroll
      for (int i=0;i<4;i++) af[i] = *(const bf16x8*)(tA + (wm*64+i*16+r16)*64 + kk*32 + quad*8);
      #pragma unroll
      for (int j=0;j<4;j++) bfr[j] = *(const bf16x8*)(tB + (wn*64+j*16+r16)*64 + kk*32 + quad*8);
      #pragma unroll
      for (int i=0;i<4;i++)
        #pragma unroll
        for (int j=0;j<4;j++)
          acc[i][j] = __builtin_amdgcn_mfma_f32_16x16x32_bf16(af[i], bfr[j], acc[i][j], 0,0,0);
    }
    __syncthreads();
  }
  #pragma unroll
  for (int j=0;j<4;j++){
    const int n = n0 + wn*64 + j*16 + r16;
    const float bi = bih[n] + bhh[n];
    #pragma unroll
    for (int i=0;i<4;i++){
      #pragma unroll
      for (int r=0;r<4;r++){
        const int m = m0 + wm*64 + i*16 + quad*4 + r;
        const int b = m >> 10, t = m & 1023;
        xw[((size_t)t*BB + b)*G4 + n] = acc[i][j][r] + bi;
      }
    }
  }
}

// ---------------- K2: persistent encoder LSTM + fused positional LSTM -----------------
// blocks 0..127: producers (4 hidden units each, Whh slice in VGPRs, f32).
// blocks 128..131: per-batch P-LSTM consumers.
// h published to encg as (h+2.0) in (1,3) via agent-scope atomics; data-as-flag vs 0xAA.
// This version: per-lane b64 spin (no barrier per poll round), double-buffered LDS h,
// fast gates (v_exp/v_rcp) on the publish critical path.
__global__ __launch_bounds__(256) void k2_encoder(
  const float* __restrict__ xw, const float* __restrict__ cWhh,
  const int* __restrict__ padl,
  const unsigned short* __restrict__ cWpih, const float* __restrict__ cSmall,
  uint32_t* encg, float* __restrict__ encf, float* __restrict__ mug, float* __restrict__ invg)
{
  struct SProd { float hs[2][BB][HH]; float gpre[16][BB]; };
  struct SPos  { float he[2][HH]; float xg[GP]; float hp[PP]; float wphh[GP][PP];
                 float bpi[GP]; float bph[GP]; float wmu[3][PP]; float bm[3];
                 float wsg[PP]; float bs1; float msh[4]; };
  __shared__ union { SProd a; SPos b; } sh;

  const int blk = blockIdx.x, tid = threadIdx.x;

  if (blk < 128) {
    // ---------------- producer ----------------
    const int u0 = blk*4;
    const int row = tid >> 4, s = tid & 15;      // 16 gate-rows x 16 col-segments
    const int g = row >> 2, uu = row & 3;
    const int grow = g*HH + u0 + uu;             // gate row in [0,2048)
    float wreg[32];
    #pragma unroll
    for (int k=0;k<8;k++)
      #pragma unroll
      for (int j=0;j<4;j++)
        wreg[k*4+j] = cWhh[(size_t)grow*HH + 4*s + 64*k + j];
    float c_st = 0.f;                            // cell state for (b=tid&3, cu=tid>>2), tid<16
    for (int i=tid;i<BB*HH;i+=256) ((float*)sh.a.hs[0])[i] = 0.f;
    __syncthreads();

    for (int t=0;t<TT;t++){
      const int cur = t & 1;
      float xwv0=0,xwv1=0,xwv2=0,xwv3=0;
      if (s==0){
        const float* xp = xw + (size_t)t*BB*G4 + grow;
        xwv0 = xp[0]; xwv1 = xp[G4]; xwv2 = xp[2*G4]; xwv3 = xp[3*G4];
      }
      if (t > 0){
        // per-lane spin: 4 qwords per thread, retry only missing words, no barrier/round
        const uint64_t* src = (const uint64_t*)(encg + (size_t)(t-1)*BB*HH) + (size_t)tid*4;
        uint64_t hv[4]; uint32_t got = 0; int tries = 0;
        while (got != 0xFu){
          #pragma unroll
          for (int w=0; w<4; w++){
            if (!(got & (1u<<w))){
              uint64_t v = __hip_atomic_load(src + w, __ATOMIC_RELAXED, __HIP_MEMORY_SCOPE_AGENT);
              if ((uint32_t)v != POISON && (uint32_t)(v>>32) != POISON){ hv[w] = v; got |= (1u<<w); }
            }
          }
          if (++tries > 16384){                  // failsafe: never hang (h -> 0)
            #pragma unroll
            for (int w=0; w<4; w++) if (!(got & (1u<<w))) hv[w] = 0x4000000040000000ull;
            got = 0xFu;
          }
        }
        float* dst = (float*)sh.a.hs[cur] + tid*8;
        #pragma unroll
        for (int w=0; w<4; w++){
          dst[2*w]   = __uint_as_float((uint32_t)(hv[w]      )) - 2.0f;
          dst[2*w+1] = __uint_as_float((uint32_t)(hv[w] >> 32)) - 2.0f;
        }
      }
      __syncthreads();                           // hs[cur] ready (double-buffered: 1 barrier)
      float p0=0.f,p1=0.f,p2=0.f,p3=0.f;
      #pragma unroll
      for (int k=0;k<8;k++){
        const int cb = 4*s + 64*k;
        const f32x4 h0 = *(const f32x4*)&sh.a.hs[cur][0][cb];
        const f32x4 h1 = *(const f32x4*)&sh.a.hs[cur][1][cb];
        const f32x4 h2 = *(const f32x4*)&sh.a.hs[cur][2][cb];
        const f32x4 h3 = *(const f32x4*)&sh.a.hs[cur][3][cb];
        const float w0=wreg[k*4],w1=wreg[k*4+1],w2=wreg[k*4+2],w3=wreg[k*4+3];
        p0 += w0*h0.x + w1*h0.y + w2*h0.z + w3*h0.w;
        p1 += w0*h1.x + w1*h1.y + w2*h1.z + w3*h1.w;
        p2 += w0*h2.x + w1*h2.y + w2*h2.z + w3*h2.w;
        p3 += w0*h3.x + w1*h3.y + w2*h3.z + w3*h3.w;
      }
      #pragma unroll
      for (int d=1; d<16; d<<=1){
        p0 += __shfl_xor(p0,d); p1 += __shfl_xor(p1,d);
        p2 += __shfl_xor(p2,d); p3 += __shfl_xor(p3,d);
      }
      if (s==0){
        sh.a.gpre[row][0] = p0 + xwv0;           // bhh folded into xw by k1
        sh.a.gpre[row][1] = p1 + xwv1;
        sh.a.gpre[row][2] = p2 + xwv2;
        sh.a.gpre[row][3] = p3 + xwv3;
      }
      __syncthreads();
      if (tid < 16){
        const int b = tid & 3, cu = tid >> 2;
        const float gi = sh.a.gpre[cu][b];
        const float gf = sh.a.gpre[4+cu][b];
        const float gg = sh.a.gpre[8+cu][b];
        const float go = sh.a.gpre[12+cu][b];
        c_st = fsigm(gf)*c_st + fsigm(gi)*ftanh(gg);
        const float h = fsigm(go)*ftanh(c_st);
        __hip_atomic_store(encg + (size_t)t*BB*HH + b*HH + u0 + cu,
                           __float_as_uint(h + 2.0f),
                           __ATOMIC_RELAXED, __HIP_MEMORY_SCOPE_AGENT);
        encf[((size_t)b*TT + t)*HH + u0 + cu] = h;
      }
    }
  } else {
    // ---------------- positional LSTM, one block per batch ----------------
    const int b = blk - 128;
    // cSmall float layout: wphh[1600] bpi[80] bph[80] wmu[60] bmu[3] wsig[20] bsig[1] bc[512]
    uint32_t wr[128];                            // Wp_ih bf16 pairs: row tid>>1, half tid&1
    if (tid < 160){
      const uint32_t* g = (const uint32_t*)(cWpih + (size_t)(tid>>1)*HH + (size_t)(tid&1)*256);
      #pragma unroll
      for (int i=0;i<128;i++) wr[i] = g[i];
    }
    for (int i=tid;i<GP*PP;i+=256) ((float*)sh.b.wphh)[i] = cSmall[i];
    for (int i=tid;i<GP;i+=256){ sh.b.bpi[i] = cSmall[1600+i]; sh.b.bph[i] = cSmall[1680+i]; }
    if (tid < 3*PP) ((float*)sh.b.wmu)[tid] = cSmall[1760+tid];
    if (tid < 3) sh.b.bm[tid] = cSmall[1820+tid];
    if (tid < PP) sh.b.wsg[tid] = cSmall[1823+tid];
    if (tid == 0) sh.b.bs1 = cSmall[1843];
    if (tid < PP) sh.b.hp[tid] = 0.f;
    const float invL = 1.0f / (float)padl[b];
    float mu_prev = 0.f, c_p = 0.f;
    __syncthreads();

    for (int t=0;t<TT;t++){
      const int cur = t & 1;
      // per-lane b64 spin: 1 qword per thread
      const uint64_t* src = (const uint64_t*)(encg + ((size_t)t*BB + b)*HH) + tid;
      uint64_t v = 0x4000000040000000ull; int tries = 0;
      for (;;){
        uint64_t x = __hip_atomic_load(src, __ATOMIC_RELAXED, __HIP_MEMORY_SCOPE_AGENT);
        if ((uint32_t)x != POISON && (uint32_t)(x>>32) != POISON){ v = x; break; }
        if (++tries > 16384) break;              // failsafe: h -> 0
      }
      sh.b.he[cur][2*tid]   = __uint_as_float((uint32_t)(v      )) - 2.0f;
      sh.b.he[cur][2*tid+1] = __uint_as_float((uint32_t)(v >> 32)) - 2.0f;
      __syncthreads();
      float part = 0.f;
      if (tid < 160){
        const float* hv = sh.b.he[cur] + (tid&1)*256;
        #pragma unroll
        for (int i=0;i<32;i++){
          const uint32_t a0=wr[i*4],a1=wr[i*4+1],a2=wr[i*4+2],a3=wr[i*4+3];
          const f32x4 hA = *(const f32x4*)(hv + i*8);
          const f32x4 hB = *(const f32x4*)(hv + i*8 + 4);
          part += bfu((unsigned short)a0)*hA.x + bfu((unsigned short)(a0>>16))*hA.y
                + bfu((unsigned short)a1)*hA.z + bfu((unsigned short)(a1>>16))*hA.w
                + bfu((unsigned short)a2)*hB.x + bfu((unsigned short)(a2>>16))*hB.y
                + bfu((unsigned short)a3)*hB.z + bfu((unsigned short)(a3>>16))*hB.w;
        }
        part += __shfl_xor(part, 1);
      }
      if (tid < 160 && (tid&1)==0) sh.b.xg[tid>>1] = part + sh.b.bpi[tid>>1];
      __syncthreads();
      float hnew = 0.f;
      if (tid < PP){
        float pre[4];
        #pragma unroll
        for (int gg2=0; gg2<4; gg2++){
          const int r = gg2*PP + tid;
          float a = sh.b.xg[r] + sh.b.bph[r];
          #pragma unroll
          for (int k=0;k<PP;k++) a += sh.b.wphh[r][k]*sh.b.hp[k];
          pre[gg2] = a;
        }
        c_p = fsigm(pre[1])*c_p + fsigm(pre[0])*ftanh(pre[2]);
        hnew = fsigm(pre[3])*ftanh(c_p);
      }
      __syncthreads();
      if (tid < PP) sh.b.hp[tid] = hnew;
      __syncthreads();
      if (tid < 4){
        float a = 0.f;
        if (tid < 3){
          #pragma unroll
          for (int k=0;k<PP;k++) a += sh.b.wmu[tid][k]*sh.b.hp[k];
          a = fmaxf(a + sh.b.bm[tid], 0.f);
        } else {
          #pragma unroll
          for (int k=0;k<PP;k++) a += sh.b.wsg[k]*sh.b.hp[k];
          a = fsigm(a + sh.b.bs1);
        }
        sh.b.msh[tid] = a;
      }
      __syncthreads();
      if (tid == 0){
        const float m1 = sh.b.msh[0], m2 = sh.b.msh[1], m3 = sh.b.msh[2], sg = sh.b.msh[3];
        mu_prev = m1*mu_prev + (m2*invL + m3*((float)(t+1)*invL));
        mug[b*TT + t] = mu_prev;
        invg[b*TT + t] = 1.0f/(2.0f*sg*sg + 0.001f);
      }
    }
  }
}

// ---------------- K3: attention weights + ctx (fp32), 8 j's per block ----------------
__global__ __launch_bounds__(512) void k3_ctx(
  const float* __restrict__ encf, const float* __restrict__ mug,
  const float* __restrict__ invg, float* __restrict__ ctx)
{
  __shared__ float e[8][1024];
  __shared__ float rnorm[8];
  __shared__ float red[8];
  const int tid = threadIdx.x;
  const int b = blockIdx.y;
  const int j0 = (127 - (int)blockIdx.x) * 8;     // big-j blocks dispatch first
  float ps[8];
  #pragma unroll
  for (int jj=0;jj<8;jj++){
    const int j = j0 + jj;
    const float mu = mug[b*TT+j], iv = invg[b*TT+j];
    const float rj = 1.0f/(float)(j+1);
    float s_ = 0.f;
    for (int tv=tid; tv<1024; tv+=512){
      float val = 0.f;
      if (tv <= j){ const float d = (float)tv*rj - mu; val = __expf(-(d*d)*iv); }
      e[jj][tv] = val; s_ += val;
    }
    ps[jj] = s_;
  }
  #pragma unroll
  for (int jj=0;jj<8;jj++){
    float s_ = ps[jj];
    #pragma unroll
    for (int d=1; d<64; d<<=1) s_ += __shfl_xor(s_, d);
    if ((tid&63)==0) red[tid>>6] = s_;
    __syncthreads();
    if (tid==0){
      float tot = 0.f;
      #pragma unroll
      for (int w=0;w<8;w++) tot += red[w];
      rnorm[jj] = 1.0f / fmaxf(tot, 1e-12f);
    }
    __syncthreads();
  }
  const int jmax = j0 + 7;
  float acc[8];
  #pragma unroll
  for (int jj=0;jj<8;jj++) acc[jj]=0.f;
  for (int tv=0; tv<=jmax; tv++){
    const float xv = encf[((size_t)b*TT + tv)*HH + tid];
    #pragma unroll
    for (int jj=0;jj<8;jj++) acc[jj] += e[jj][tv]*xv;
  }
  #pragma unroll
  for (int jj=0;jj<8;jj++)
    ctx[((size_t)b*TT + j0+jj)*HH + tid] = acc[jj]*rnorm[jj];
}

// ---------------- K4: combined = tanh([ctx,enc] @ Wc^T + bc) (fp32), bf16 out --------
__global__ __launch_bounds__(256) void k4_combined(
  const float* __restrict__ ctx, const float* __restrict__ encf,
  const float* __restrict__ cWc, const float* __restrict__ cBc,
  unsigned short* __restrict__ comb)
{
  __shared__ float x[8][1024];
  const int tid = threadIdx.x;
  const int b = blockIdx.x >> 7;
  const int t0 = (blockIdx.x & 127) * 8;
  for (int i=tid; i<8*512; i+=256){
    const int it = i >> 9, c = i & 511;
    x[it][c]     = ctx [((size_t)b*TT + t0+it)*HH + c];
    x[it][512+c] = encf[((size_t)b*TT + t0+it)*HH + c];
  }
  __syncthreads();
  float a0[8], a1[8];
  #pragma unroll
  for (int i=0;i<8;i++){ a0[i]=0.f; a1[i]=0.f; }
  for (int k4i=0;k4i<256;k4i++){
    const f32x4 w0 = *(const f32x4*)(cWc + (size_t)tid*1024 + k4i*4);
    const f32x4 w1 = *(const f32x4*)(cWc + (size_t)(tid+256)*1024 + k4i*4);
    #pragma unroll
    for (int it=0;it<8;it++){
      const f32x4 xa = *(const f32x4*)&x[it][k4i*4];
      a0[it] += w0.x*xa.x + w0.y*xa.y + w0.z*xa.z + w0.w*xa.w;
      a1[it] += w1.x*xa.x + w1.y*xa.y + w1.z*xa.z + w1.w*xa.w;
    }
  }
  const float b0 = cBc[tid], b1 = cBc[tid+256];
  #pragma unroll
  for (int it=0;it<8;it++){
    comb[((size_t)b*1024 + t0+it)*HH + tid]       = (unsigned short)f2bf_bits(tanhf(a0[it] + b0));
    comb[((size_t)b*1024 + t0+it)*HH + tid + 256] = (unsigned short)f2bf_bits(tanhf(a1[it] + b1));
  }
}

// ---------------- K5: out = combined @ emb^T + dec_bias (bf16 MFMA, dual-dtype out) --
__global__ __launch_bounds__(256) void k5_decoder(
  const unsigned short* __restrict__ A, const unsigned short* __restrict__ emb,
  const float* __restrict__ dbias, const uint32_t* __restrict__ mode, void* __restrict__ outv)
{
  const uint32_t md = *mode;
  __shared__ __align__(16) unsigned short tA[128*64];
  __shared__ __align__(16) unsigned short tB[128*64];
  const int tid = threadIdx.x, lane = tid & 63, wid = tid >> 6;
  const int wm = wid >> 1, wn = wid & 1;
  const int m0 = blockIdx.x*128, n0 = blockIdx.y*128;
  const int srow = wid*8 + (lane>>3), skc = lane & 7;
  const int quad = lane >> 4, r16 = lane & 15;

  f32x4 acc[4][4];
  #pragma unroll
  for (int i=0;i<4;i++)
    #pragma unroll
    for (int j=0;j<4;j++) acc[i][j] = (f32x4){0.f,0.f,0.f,0.f};

  for (int k0=0;k0<HH;k0+=64){
    #pragma unroll
    for (int q=0;q<4;q++){
      gload_lds16(A + (size_t)(m0 + q*32 + srow)*HH + k0 + skc*8, (char*)tA + q*4096 + wid*1024);
      gload_lds16(emb + (size_t)(n0 + q*32 + srow)*HH + k0 + skc*8, (char*)tB + q*4096 + wid*1024);
    }
    __builtin_amdgcn_s_waitcnt(0);
    __syncthreads();
    #pragma unroll
    for (int kk=0;kk<2;kk++){
      bf16x8 af[4], bfr[4];
      #pragma unroll
      for (int i=0;i<4;i++) af[i] = *(const bf16x8*)(tA + (wm*64+i*16+r16)*64 + kk*32 + quad*8);
      #pragma unroll
      for (int j=0;j<4;j++) bfr[j] = *(const bf16x8*)(tB + (wn*64+j*16+r16)*64 + kk*32 + quad*8);
      #pragma unroll
      for (int i=0;i<4;i++)
        #pragma unroll
        for (int j=0;j<4;j++)
          acc[i][j] = __builtin_amdgcn_mfma_f32_16x16x32_bf16(af[i], bfr[j], acc[i][j], 0,0,0);
    }
    __syncthreads();
  }
  if (md){
    float* of = (float*)outv;
    #pragma unroll
    for (int j=0;j<4;j++){
      const int n = n0 + wn*64 + j*16 + r16;
      const float db = dbias[n];
      #pragma unroll
      for (int i=0;i<4;i++){
        #pragma unroll
        for (int r=0;r<4;r++){
          const int m = m0 + wm*64 + i*16 + quad*4 + r;
          of[(size_t)m*VV + n] = acc[i][j][r] + db;
        }
      }
    }
  } else {
    unsigned short* ob = (unsigned short*)outv;
    #pragma unroll
    for (int j=0;j<4;j++){
      const int n = n0 + wn*64 + j*16 + r16;
      const float db = dbias[n];
      #pragma unroll
      for (int i=0;i<4;i++){
        #pragma unroll
        for (int r=0;r<4;r++){
          float v = acc[i][j][r] + db;
          const float vn = __shfl_xor(v, 1);
          if ((lane&1)==0){
            const int m = m0 + wm*64 + i*16 + quad*4 + r;
            *(uint32_t*)(ob + (size_t)m*VV + n) = f2bf_bits(v) | (f2bf_bits(vn) << 16);
          }
        }
      }
    }
  }
}

// ---------------- host ----------------
extern "C" void kernel_launch(void* const* d_in, const int* in_sizes, int n_in,
                              void* d_out, int out_size, void* d_ws, size_t ws_size,
                              hipStream_t stream)
{
  (void)in_sizes; (void)n_in; (void)out_size; (void)ws_size;
  const int* ids  = (const int*)d_in[0];
  const int* padl = (const int*)d_in[1];

  char* ws = (char*)d_ws;
  // canonical bf16 copies (MFMA consumers)
  unsigned short* cE    = (unsigned short*)(ws + 0);            // 32,768,000 B
  unsigned short* cWih  = (unsigned short*)(ws + 32768000);     //  2,097,152 B
  unsigned short* cWpih = (unsigned short*)(ws + 34865152);     //     81,920 B
  // canonical f32 copies (VALU consumers)
  float* cWhh   = (float*)(ws + 34947072);                      //  4,194,304 B
  float* cWc    = (float*)(ws + 39141376);                      //  2,097,152 B
  float* cDB    = (float*)(ws + 41238528);                      //    128,000 B
  float* cBih   = (float*)(ws + 41366528);                      //      8,192 B
  float* cBhh   = (float*)(ws + 41374720);                      //      8,192 B
  float* cSmall = (float*)(ws + 41382912);                      //      9,424 B
  unsigned short* comb = (unsigned short*)(ws + ((size_t)41<<20)); // 4 MB
  float* mug  = (float*)(ws + 47185920);
  float* invg = (float*)(ws + 47202304);
  uint32_t* flag = (uint32_t*)(ws + 47218688);

  // large transient buffers live in the head of d_out (dead before k5 rewrites all of it)
  char* oh = (char*)d_out;
  uint32_t* encg = (uint32_t*)(oh + 0);                         //  8 MB [t][b][512] h+2.0
  float* xw   = (float*)(oh + 8388608);                         // 32 MB [t][b][2048]
  float* encf = (float*)(oh + 41943040);                        //  8 MB [b][t][512]
  float* ctx  = (float*)(oh + 50331648);                        //  8 MB [b][t][512]

  // mode detect + canonicalize
  k0_detect<<<1, 256, 0, stream>>>((const unsigned short*)d_in[2], flag);
  CvtTab tab;
  auto set = [&](int i, const void* s, unsigned short* db, float* df, int n){
    tab.d[i].src = s; tab.d[i].dbf = db; tab.d[i].df32 = df; tab.d[i].n = n; };
  set(0,  d_in[2],  cE,    nullptr,      16384000);  // emb
  set(1,  d_in[3],  nullptr, cDB,        32000);     // dec_bias
  set(2,  d_in[4],  cWih,  nullptr,      1048576);   // Wih
  set(3,  d_in[5],  nullptr, cWhh,       1048576);   // Whh
  set(4,  d_in[6],  nullptr, cBih,       2048);      // bih
  set(5,  d_in[7],  nullptr, cBhh,       2048);      // bhh
  set(6,  d_in[8],  cWpih, nullptr,      40960);     // Wp_ih
  set(7,  d_in[9],  nullptr, cSmall+0,   1600);      // Wp_hh
  set(8,  d_in[10], nullptr, cSmall+1600, 80);       // bp_ih
  set(9,  d_in[11], nullptr, cSmall+1680, 80);       // bp_hh
  set(10, d_in[12], nullptr, cSmall+1760, 60);       // Wmu
  set(11, d_in[13], nullptr, cSmall+1820, 3);        // bmu
  set(12, d_in[14], nullptr, cSmall+1823, 20);       // Wsig
  set(13, d_in[15], nullptr, cSmall+1843, 1);        // bsig
  set(14, d_in[16], nullptr, cWc,        524288);    // Wc
  set(15, d_in[17], nullptr, cSmall+1844, 512);      // bc
  kC_convert<<<dim3(256,16), 256, 0, stream>>>(tab, flag);

  // poison the h-exchange region ourselves so data-as-flag is self-contained
  hipMemsetAsync(encg, 0xAA, (size_t)TT*BB*HH*4, stream);
  k1_embed_xw<<<dim3(32,16), 256, 0, stream>>>(ids, cE, cWih, cBih, cBhh, xw);
  k2_encoder<<<dim3(132), 256, 0, stream>>>(xw, cWhh, padl, cWpih, cSmall,
                                            encg, encf, mug, invg);
  k3_ctx<<<dim3(128,4), 512, 0, stream>>>(encf, mug, invg, ctx);
  k4_combined<<<dim3(512), 256, 0, stream>>>(ctx, encf, cWc, cSmall+1844, comb);
  k5_decoder<<<dim3(32,250), 256, 0, stream>>>(comb, cE, cDB, flag, d_out);
}

// Round 3
// 5837.681 us; speedup vs baseline: 1.0096x; 1.0096x over previous
//
#include <hip/hip_runtime.h>
#include <hip/hip_bf16.h>
#include <stdint.h>

#define TT 1024
#define BB 4
#define HH 512
#define PP 20
#define VV 32000
#define G4 2048
#define GP 80
#define POISON 0xAAAAAAAAu

typedef __bf16 bf16x8 __attribute__((ext_vector_type(8)));
typedef float f32x4 __attribute__((ext_vector_type(4)));
typedef uint32_t u32x4 __attribute__((ext_vector_type(4)));

__device__ __forceinline__ float bfu(unsigned short u){ return __uint_as_float(((uint32_t)u)<<16); }
__device__ __forceinline__ uint32_t f2bf_bits(float f){
  uint32_t u = __float_as_uint(f);
  return (u + 0x7FFFu + ((u>>16)&1u)) >> 16;
}
// fast, saturation-safe sigmoid/tanh (v_exp_f32 + v_rcp_f32, ~2 ulp)
__device__ __forceinline__ float fsigm(float x){
  return __builtin_amdgcn_rcpf(1.0f + __expf(-x));
}
__device__ __forceinline__ float ftanh(float x){
  return 1.0f - 2.0f*__builtin_amdgcn_rcpf(__expf(2.0f*x) + 1.0f);
}

__device__ __forceinline__ void gload_lds16(const void* g, void* l){
  __builtin_amdgcn_global_load_lds((__attribute__((address_space(1))) void*)(g),
                                   (__attribute__((address_space(3))) void*)(l), 16, 0, 0);
}

// 32B coherent poll load: two dwordx4 with sc1 (agent-scope, L2-bypassing — same flag
// the compiler emits for __hip_atomic_load AGENT relaxed, but 16B per request).
__device__ __forceinline__ void load2x16_sc1(const uint32_t* p, u32x4& a, u32x4& b){
  asm volatile("global_load_dwordx4 %0, %2, off sc1\n\t"
               "global_load_dwordx4 %1, %2, off offset:16 sc1\n\t"
               "s_waitcnt vmcnt(0)"
               : "=&v"(a), "=&v"(b) : "v"(p) : "memory");
}

// ---------------- K0: detect input float width (bf16 vs f32) --------------------------
__global__ void k0_detect(const unsigned short* __restrict__ emb_raw, uint32_t* __restrict__ flag){
  __shared__ int cnt;
  if (threadIdx.x==0) cnt = 0;
  __syncthreads();
  int c = 0;
  for (int i=threadIdx.x; i<8192; i+=256){
    float f = bfu(emb_raw[i]);
    if (fabsf(f) >= 0.25f) c++;
  }
  atomicAdd(&cnt, c);
  __syncthreads();
  if (threadIdx.x==0) *flag = (cnt > 64) ? 1u : 0u;   // 1 = f32 inputs
}

// ---------------- KC: canonicalize float inputs -> bf16 and/or f32 copies -------------
struct CvtDesc { const void* src; unsigned short* dbf; float* df32; int n; };
struct CvtTab  { CvtDesc d[16]; };

__global__ __launch_bounds__(256) void kC_convert(CvtTab tab, const uint32_t* __restrict__ flag){
  const uint32_t md = *flag;
  const CvtDesc de = tab.d[blockIdx.y];
  const int stride = gridDim.x * 256;
  for (int i = blockIdx.x*256 + threadIdx.x; i < de.n; i += stride){
    float v;
    if (md) v = ((const float*)de.src)[i];
    else    v = bfu(((const unsigned short*)de.src)[i]);
    if (de.dbf)  de.dbf[i]  = (unsigned short)f2bf_bits(v);
    if (de.df32) de.df32[i] = v;
  }
}

// ---------------- K1: x = emb[ids]; xw = x @ Wih^T + (bih + bhh) (bf16 MFMA) ----------
__global__ __launch_bounds__(256) void k1_embed_xw(
    const int* __restrict__ ids, const unsigned short* __restrict__ emb,
    const unsigned short* __restrict__ Wih, const float* __restrict__ bih,
    const float* __restrict__ bhh, float* __restrict__ xw)
{
  __shared__ __align__(16) unsigned short tA[128*64];
  __shared__ __align__(16) unsigned short tB[128*64];
  const int tid = threadIdx.x, lane = tid & 63, wid = tid >> 6;
  const int wm = wid >> 1, wn = wid & 1;
  const int m0 = blockIdx.x*128, n0 = blockIdx.y*128;
  const int srow = wid*8 + (lane>>3), skc = lane & 7;
  const int quad = lane >> 4, r16 = lane & 15;

  int aid[4];
  #pragma unroll
  for (int q=0;q<4;q++) aid[q] = ids[m0 + q*32 + srow];

  f32x4 acc[4][4];
  #pragma unroll
  for (int i=0;i<4;i++)
    #pragma unroll
    for (int j=0;j<4;j++) acc[i][j] = (f32x4){0.f,0.f,0.f,0.f};

  for (int k0=0;k0<HH;k0+=64){
    #pragma unroll
    for (int q=0;q<4;q++){
      gload_lds16(emb + (size_t)aid[q]*HH + k0 + skc*8, (char*)tA + q*4096 + wid*1024);
      gload_lds16(Wih + (size_t)(n0 + q*32 + srow)*HH + k0 + skc*8, (char*)tB + q*4096 + wid*1024);
    }
    __builtin_amdgcn_s_waitcnt(0);
    __syncthreads();
    #pragma unroll
    for (int kk=0;kk<2;kk++){
      bf16x8 af[4], bfr[4];
      #pragma unroll
      for (int i=0;i<4;i++) af[i] = *(const bf16x8*)(tA + (wm*64+i*16+r16)*64 + kk*32 + quad*8);
      #pragma unroll
      for (int j=0;j<4;j++) bfr[j] = *(const bf16x8*)(tB + (wn*64+j*16+r16)*64 + kk*32 + quad*8);
      #pragma unroll
      for (int i=0;i<4;i++)
        #pragma unroll
        for (int j=0;j<4;j++)
          acc[i][j] = __builtin_amdgcn_mfma_f32_16x16x32_bf16(af[i], bfr[j], acc[i][j], 0,0,0);
    }
    __syncthreads();
  }
  #pragma unroll
  for (int j=0;j<4;j++){
    const int n = n0 + wn*64 + j*16 + r16;
    const float bi = bih[n] + bhh[n];
    #pragma unroll
    for (int i=0;i<4;i++){
      #pragma unroll
      for (int r=0;r<4;r++){
        const int m = m0 + wm*64 + i*16 + quad*4 + r;
        const int b = m >> 10, t = m & 1023;
        xw[((size_t)t*BB + b)*G4 + n] = acc[i][j][r] + bi;
      }
    }
  }
}

// ---------------- K2: persistent encoder LSTM + fused positional LSTM -----------------
// blocks 0..63: producers (8 hidden units each, 64 Whh weights/thread in VGPRs, f32).
// blocks 64..67: per-batch P-LSTM consumers.
// h published to encg as (h+2.0) in (1,3) via agent-scope atomics; data-as-flag vs 0xAA.
// 64 fat producer blocks (half the polling population) + 16B sc1 poll loads
// (half the requests/thread) -> ~4x less coherent poll traffic per step vs R0.
__global__ __launch_bounds__(256) void k2_encoder(
  const float* __restrict__ xw, const float* __restrict__ cWhh,
  const int* __restrict__ padl,
  const unsigned short* __restrict__ cWpih, const float* __restrict__ cSmall,
  uint32_t* encg, float* __restrict__ encf, float* __restrict__ mug, float* __restrict__ invg)
{
  struct SProd { float hs[2][BB][HH]; float gpre[32][BB]; };
  struct SPos  { float he[2][HH]; float xg[GP]; float hp[PP]; float wphh[GP][PP];
                 float bpi[GP]; float bph[GP]; float wmu[3][PP]; float bm[3];
                 float wsg[PP]; float bs1; float msh[4]; };
  __shared__ union { SProd a; SPos b; } sh;

  const int blk = blockIdx.x, tid = threadIdx.x;

  if (blk < 64) {
    // ---------------- producer: 8 units, 32 gate-rows x 8 col-segments ----------------
    const int u0 = blk*8;
    const int row = tid >> 3, s = tid & 7;       // row in [0,32), seg in [0,8)
    const int g = row >> 3, uu = row & 7;
    const int grow = g*HH + u0 + uu;             // gate row in [0,2048)
    float wreg[64];
    #pragma unroll
    for (int k=0;k<16;k++)
      #pragma unroll
      for (int j=0;j<4;j++)
        wreg[k*4+j] = cWhh[(size_t)grow*HH + 4*s + 32*k + j];
    float c_st = 0.f;                            // cell state for (b=tid&3, cu=tid>>2), tid<32
    for (int i=tid;i<BB*HH;i+=256) ((float*)sh.a.hs[0])[i] = 0.f;
    __syncthreads();

    for (int t=0;t<TT;t++){
      const int cur = t & 1;
      float xwv0=0,xwv1=0,xwv2=0,xwv3=0;
      if (s==0){
        const float* xp = xw + (size_t)t*BB*G4 + grow;
        xwv0 = xp[0]; xwv1 = xp[G4]; xwv2 = xp[2*G4]; xwv3 = xp[3*G4];
      }
      if (t > 0){
        // per-lane spin: 2 x 16B sc1 loads, word-granular data-as-flag
        const uint32_t* src = encg + (size_t)(t-1)*BB*HH + tid*8;
        u32x4 va, vb; int tries = 0;
        for (;;){
          load2x16_sc1(src, va, vb);
          bool ok = true;
          #pragma unroll
          for (int w=0;w<4;w++){ if (va[w]==POISON) ok=false; if (vb[w]==POISON) ok=false; }
          if (ok) break;
          if (++tries > 16384){                  // failsafe: never hang (h -> 0)
            #pragma unroll
            for (int w=0;w<4;w++){ if (va[w]==POISON) va[w]=0x40000000u; if (vb[w]==POISON) vb[w]=0x40000000u; }
            break;
          }
        }
        float* dst = (float*)sh.a.hs[cur] + tid*8;
        #pragma unroll
        for (int w=0; w<4; w++){
          dst[w]   = __uint_as_float(va[w]) - 2.0f;
          dst[4+w] = __uint_as_float(vb[w]) - 2.0f;
        }
      }
      __syncthreads();                           // hs[cur] ready
      float p0=0.f,p1=0.f,p2=0.f,p3=0.f;
      #pragma unroll
      for (int k=0;k<16;k++){
        const int cb = 4*s + 32*k;
        const f32x4 h0 = *(const f32x4*)&sh.a.hs[cur][0][cb];
        const f32x4 h1 = *(const f32x4*)&sh.a.hs[cur][1][cb];
        const f32x4 h2 = *(const f32x4*)&sh.a.hs[cur][2][cb];
        const f32x4 h3 = *(const f32x4*)&sh.a.hs[cur][3][cb];
        const float w0=wreg[k*4],w1=wreg[k*4+1],w2=wreg[k*4+2],w3=wreg[k*4+3];
        p0 += w0*h0.x + w1*h0.y + w2*h0.z + w3*h0.w;
        p1 += w0*h1.x + w1*h1.y + w2*h1.z + w3*h1.w;
        p2 += w0*h2.x + w1*h2.y + w2*h2.z + w3*h2.w;
        p3 += w0*h3.x + w1*h3.y + w2*h3.z + w3*h3.w;
      }
      #pragma unroll
      for (int d=1; d<8; d<<=1){
        p0 += __shfl_xor(p0,d); p1 += __shfl_xor(p1,d);
        p2 += __shfl_xor(p2,d); p3 += __shfl_xor(p3,d);
      }
      if (s==0){
        sh.a.gpre[row][0] = p0 + xwv0;           // bhh folded into xw by k1
        sh.a.gpre[row][1] = p1 + xwv1;
        sh.a.gpre[row][2] = p2 + xwv2;
        sh.a.gpre[row][3] = p3 + xwv3;
      }
      __syncthreads();
      if (tid < 32){
        const int b = tid & 3, cu = tid >> 2;    // cu = unit within block, [0,8)
        const float gi = sh.a.gpre[cu][b];
        const float gf = sh.a.gpre[8+cu][b];
        const float gg = sh.a.gpre[16+cu][b];
        const float go = sh.a.gpre[24+cu][b];
        c_st = fsigm(gf)*c_st + fsigm(gi)*ftanh(gg);
        const float h = fsigm(go)*ftanh(c_st);
        __hip_atomic_store(encg + (size_t)t*BB*HH + b*HH + u0 + cu,
                           __float_as_uint(h + 2.0f),
                           __ATOMIC_RELAXED, __HIP_MEMORY_SCOPE_AGENT);
        encf[((size_t)b*TT + t)*HH + u0 + cu] = h;
      }
    }
  } else {
    // ---------------- positional LSTM, one block per batch ----------------
    const int b = blk - 64;
    uint32_t wr[128];                            // Wp_ih bf16 pairs: row tid>>1, half tid&1
    if (tid < 160){
      const uint32_t* g = (const uint32_t*)(cWpih + (size_t)(tid>>1)*HH + (size_t)(tid&1)*256);
      #pragma unroll
      for (int i=0;i<128;i++) wr[i] = g[i];
    }
    for (int i=tid;i<GP*PP;i+=256) ((float*)sh.b.wphh)[i] = cSmall[i];
    for (int i=tid;i<GP;i+=256){ sh.b.bpi[i] = cSmall[1600+i]; sh.b.bph[i] = cSmall[1680+i]; }
    if (tid < 3*PP) ((float*)sh.b.wmu)[tid] = cSmall[1760+tid];
    if (tid < 3) sh.b.bm[tid] = cSmall[1820+tid];
    if (tid < PP) sh.b.wsg[tid] = cSmall[1823+tid];
    if (tid == 0) sh.b.bs1 = cSmall[1843];
    if (tid < PP) sh.b.hp[tid] = 0.f;
    const float invL = 1.0f / (float)padl[b];
    float mu_prev = 0.f, c_p = 0.f;
    __syncthreads();

    for (int t=0;t<TT;t++){
      const int cur = t & 1;
      const uint64_t* src = (const uint64_t*)(encg + ((size_t)t*BB + b)*HH) + tid;
      uint64_t v = 0x4000000040000000ull; int tries = 0;
      for (;;){
        uint64_t x = __hip_atomic_load(src, __ATOMIC_RELAXED, __HIP_MEMORY_SCOPE_AGENT);
        if ((uint32_t)x != POISON && (uint32_t)(x>>32) != POISON){ v = x; break; }
        if (++tries > 16384) break;              // failsafe: h -> 0
      }
      sh.b.he[cur][2*tid]   = __uint_as_float((uint32_t)(v      )) - 2.0f;
      sh.b.he[cur][2*tid+1] = __uint_as_float((uint32_t)(v >> 32)) - 2.0f;
      __syncthreads();
      float part = 0.f;
      if (tid < 160){
        const float* hv = sh.b.he[cur] + (tid&1)*256;
        #pragma unroll
        for (int i=0;i<32;i++){
          const uint32_t a0=wr[i*4],a1=wr[i*4+1],a2=wr[i*4+2],a3=wr[i*4+3];
          const f32x4 hA = *(const f32x4*)(hv + i*8);
          const f32x4 hB = *(const f32x4*)(hv + i*8 + 4);
          part += bfu((unsigned short)a0)*hA.x + bfu((unsigned short)(a0>>16))*hA.y
                + bfu((unsigned short)a1)*hA.z + bfu((unsigned short)(a1>>16))*hA.w
                + bfu((unsigned short)a2)*hB.x + bfu((unsigned short)(a2>>16))*hB.y
                + bfu((unsigned short)a3)*hB.z + bfu((unsigned short)(a3>>16))*hB.w;
        }
        part += __shfl_xor(part, 1);
      }
      if (tid < 160 && (tid&1)==0) sh.b.xg[tid>>1] = part + sh.b.bpi[tid>>1];
      __syncthreads();
      float hnew = 0.f;
      if (tid < PP){
        float pre[4];
        #pragma unroll
        for (int gg2=0; gg2<4; gg2++){
          const int r = gg2*PP + tid;
          float a = sh.b.xg[r] + sh.b.bph[r];
          #pragma unroll
          for (int k=0;k<PP;k++) a += sh.b.wphh[r][k]*sh.b.hp[k];
          pre[gg2] = a;
        }
        c_p = fsigm(pre[1])*c_p + fsigm(pre[0])*ftanh(pre[2]);
        hnew = fsigm(pre[3])*ftanh(c_p);
      }
      __syncthreads();
      if (tid < PP) sh.b.hp[tid] = hnew;
      __syncthreads();
      if (tid < 4){
        float a = 0.f;
        if (tid < 3){
          #pragma unroll
          for (int k=0;k<PP;k++) a += sh.b.wmu[tid][k]*sh.b.hp[k];
          a = fmaxf(a + sh.b.bm[tid], 0.f);
        } else {
          #pragma unroll
          for (int k=0;k<PP;k++) a += sh.b.wsg[k]*sh.b.hp[k];
          a = fsigm(a + sh.b.bs1);
        }
        sh.b.msh[tid] = a;
      }
      __syncthreads();
      if (tid == 0){
        const float m1 = sh.b.msh[0], m2 = sh.b.msh[1], m3 = sh.b.msh[2], sg = sh.b.msh[3];
        mu_prev = m1*mu_prev + (m2*invL + m3*((float)(t+1)*invL));
        mug[b*TT + t] = mu_prev;
        invg[b*TT + t] = 1.0f/(2.0f*sg*sg + 0.001f);
      }
    }
  }
}

// ---------------- K3: attention weights + ctx (fp32), 8 j's per block ----------------
__global__ __launch_bounds__(512) void k3_ctx(
  const float* __restrict__ encf, const float* __restrict__ mug,
  const float* __restrict__ invg, float* __restrict__ ctx)
{
  __shared__ float e[8][1024];
  __shared__ float rnorm[8];
  __shared__ float red[8];
  const int tid = threadIdx.x;
  const int b = blockIdx.y;
  const int j0 = (127 - (int)blockIdx.x) * 8;     // big-j blocks dispatch first
  float ps[8];
  #pragma unroll
  for (int jj=0;jj<8;jj++){
    const int j = j0 + jj;
    const float mu = mug[b*TT+j], iv = invg[b*TT+j];
    const float rj = 1.0f/(float)(j+1);
    float s_ = 0.f;
    for (int tv=tid; tv<1024; tv+=512){
      float val = 0.f;
      if (tv <= j){ const float d = (float)tv*rj - mu; val = __expf(-(d*d)*iv); }
      e[jj][tv] = val; s_ += val;
    }
    ps[jj] = s_;
  }
  #pragma unroll
  for (int jj=0;jj<8;jj++){
    float s_ = ps[jj];
    #pragma unroll
    for (int d=1; d<64; d<<=1) s_ += __shfl_xor(s_, d);
    if ((tid&63)==0) red[tid>>6] = s_;
    __syncthreads();
    if (tid==0){
      float tot = 0.f;
      #pragma unroll
      for (int w=0;w<8;w++) tot += red[w];
      rnorm[jj] = 1.0f / fmaxf(tot, 1e-12f);
    }
    __syncthreads();
  }
  const int jmax = j0 + 7;
  float acc[8];
  #pragma unroll
  for (int jj=0;jj<8;jj++) acc[jj]=0.f;
  for (int tv=0; tv<=jmax; tv++){
    const float xv = encf[((size_t)b*TT + tv)*HH + tid];
    #pragma unroll
    for (int jj=0;jj<8;jj++) acc[jj] += e[jj][tv]*xv;
  }
  #pragma unroll
  for (int jj=0;jj<8;jj++)
    ctx[((size_t)b*TT + j0+jj)*HH + tid] = acc[jj]*rnorm[jj];
}

// ---------------- K4: combined = tanh([ctx,enc] @ Wc^T + bc) (fp32), bf16 out --------
__global__ __launch_bounds__(256) void k4_combined(
  const float* __restrict__ ctx, const float* __restrict__ encf,
  const float* __restrict__ cWc, const float* __restrict__ cBc,
  unsigned short* __restrict__ comb)
{
  __shared__ float x[8][1024];
  const int tid = threadIdx.x;
  const int b = blockIdx.x >> 7;
  const int t0 = (blockIdx.x & 127) * 8;
  for (int i=tid; i<8*512; i+=256){
    const int it = i >> 9, c = i & 511;
    x[it][c]     = ctx [((size_t)b*TT + t0+it)*HH + c];
    x[it][512+c] = encf[((size_t)b*TT + t0+it)*HH + c];
  }
  __syncthreads();
  float a0[8], a1[8];
  #pragma unroll
  for (int i=0;i<8;i++){ a0[i]=0.f; a1[i]=0.f; }
  for (int k4i=0;k4i<256;k4i++){
    const f32x4 w0 = *(const f32x4*)(cWc + (size_t)tid*1024 + k4i*4);
    const f32x4 w1 = *(const f32x4*)(cWc + (size_t)(tid+256)*1024 + k4i*4);
    #pragma unroll
    for (int it=0;it<8;it++){
      const f32x4 xa = *(const f32x4*)&x[it][k4i*4];
      a0[it] += w0.x*xa.x + w0.y*xa.y + w0.z*xa.z + w0.w*xa.w;
      a1[it] += w1.x*xa.x + w1.y*xa.y + w1.z*xa.z + w1.w*xa.w;
    }
  }
  const float b0 = cBc[tid], b1 = cBc[tid+256];
  #pragma unroll
  for (int it=0;it<8;it++){
    comb[((size_t)b*1024 + t0+it)*HH + tid]       = (unsigned short)f2bf_bits(tanhf(a0[it] + b0));
    comb[((size_t)b*1024 + t0+it)*HH + tid + 256] = (unsigned short)f2bf_bits(tanhf(a1[it] + b1));
  }
}

// ---------------- K5: out = combined @ emb^T + dec_bias (bf16 MFMA, dual-dtype out) --
__global__ __launch_bounds__(256) void k5_decoder(
  const unsigned short* __restrict__ A, const unsigned short* __restrict__ emb,
  const float* __restrict__ dbias, const uint32_t* __restrict__ mode, void* __restrict__ outv)
{
  const uint32_t md = *mode;
  __shared__ __align__(16) unsigned short tA[128*64];
  __shared__ __align__(16) unsigned short tB[128*64];
  const int tid = threadIdx.x, lane = tid & 63, wid = tid >> 6;
  const int wm = wid >> 1, wn = wid & 1;
  const int m0 = blockIdx.x*128, n0 = blockIdx.y*128;
  const int srow = wid*8 + (lane>>3), skc = lane & 7;
  const int quad = lane >> 4, r16 = lane & 15;

  f32x4 acc[4][4];
  #pragma unroll
  for (int i=0;i<4;i++)
    #pragma unroll
    for (int j=0;j<4;j++) acc[i][j] = (f32x4){0.f,0.f,0.f,0.f};

  for (int k0=0;k0<HH;k0+=64){
    #pragma unroll
    for (int q=0;q<4;q++){
      gload_lds16(A + (size_t)(m0 + q*32 + srow)*HH + k0 + skc*8, (char*)tA + q*4096 + wid*1024);
      gload_lds16(emb + (size_t)(n0 + q*32 + srow)*HH + k0 + skc*8, (char*)tB + q*4096 + wid*1024);
    }
    __builtin_amdgcn_s_waitcnt(0);
    __syncthreads();
    #pragma unroll
    for (int kk=0;kk<2;kk++){
      bf16x8 af[4], bfr[4];
      #pragma unroll
      for (int i=0;i<4;i++) af[i] = *(const bf16x8*)(tA + (wm*64+i*16+r16)*64 + kk*32 + quad*8);
      #pragma unroll
      for (int j=0;j<4;j++) bfr[j] = *(const bf16x8*)(tB + (wn*64+j*16+r16)*64 + kk*32 + quad*8);
      #pragma unroll
      for (int i=0;i<4;i++)
        #pragma unroll
        for (int j=0;j<4;j++)
          acc[i][j] = __builtin_amdgcn_mfma_f32_16x16x32_bf16(af[i], bfr[j], acc[i][j], 0,0,0);
    }
    __syncthreads();
  }
  if (md){
    float* of = (float*)outv;
    #pragma unroll
    for (int j=0;j<4;j++){
      const int n = n0 + wn*64 + j*16 + r16;
      const float db = dbias[n];
      #pragma unroll
      for (int i=0;i<4;i++){
        #pragma unroll
        for (int r=0;r<4;r++){
          const int m = m0 + wm*64 + i*16 + quad*4 + r;
          of[(size_t)m*VV + n] = acc[i][j][r] + db;
        }
      }
    }
  } else {
    unsigned short* ob = (unsigned short*)outv;
    #pragma unroll
    for (int j=0;j<4;j++){
      const int n = n0 + wn*64 + j*16 + r16;
      const float db = dbias[n];
      #pragma unroll
      for (int i=0;i<4;i++){
        #pragma unroll
        for (int r=0;r<4;r++){
          float v = acc[i][j][r] + db;
          const float vn = __shfl_xor(v, 1);
          if ((lane&1)==0){
            const int m = m0 + wm*64 + i*16 + quad*4 + r;
            *(uint32_t*)(ob + (size_t)m*VV + n) = f2bf_bits(v) | (f2bf_bits(vn) << 16);
          }
        }
      }
    }
  }
}

// ---------------- host ----------------
extern "C" void kernel_launch(void* const* d_in, const int* in_sizes, int n_in,
                              void* d_out, int out_size, void* d_ws, size_t ws_size,
                              hipStream_t stream)
{
  (void)in_sizes; (void)n_in; (void)out_size; (void)ws_size;
  const int* ids  = (const int*)d_in[0];
  const int* padl = (const int*)d_in[1];

  char* ws = (char*)d_ws;
  unsigned short* cE    = (unsigned short*)(ws + 0);            // 32,768,000 B
  unsigned short* cWih  = (unsigned short*)(ws + 32768000);     //  2,097,152 B
  unsigned short* cWpih = (unsigned short*)(ws + 34865152);     //     81,920 B
  float* cWhh   = (float*)(ws + 34947072);                      //  4,194,304 B
  float* cWc    = (float*)(ws + 39141376);                      //  2,097,152 B
  float* cDB    = (float*)(ws + 41238528);                      //    128,000 B
  float* cBih   = (float*)(ws + 41366528);                      //      8,192 B
  float* cBhh   = (float*)(ws + 41374720);                      //      8,192 B
  float* cSmall = (float*)(ws + 41382912);                      //      9,424 B
  unsigned short* comb = (unsigned short*)(ws + ((size_t)41<<20)); // 4 MB
  float* mug  = (float*)(ws + 47185920);
  float* invg = (float*)(ws + 47202304);
  uint32_t* flag = (uint32_t*)(ws + 47218688);

  char* oh = (char*)d_out;
  uint32_t* encg = (uint32_t*)(oh + 0);                         //  8 MB [t][b][512] h+2.0
  float* xw   = (float*)(oh + 8388608);                         // 32 MB [t][b][2048]
  float* encf = (float*)(oh + 41943040);                        //  8 MB [b][t][512]
  float* ctx  = (float*)(oh + 50331648);                        //  8 MB [b][t][512]

  k0_detect<<<1, 256, 0, stream>>>((const unsigned short*)d_in[2], flag);
  CvtTab tab;
  auto set = [&](int i, const void* s, unsigned short* db, float* df, int n){
    tab.d[i].src = s; tab.d[i].dbf = db; tab.d[i].df32 = df; tab.d[i].n = n; };
  set(0,  d_in[2],  cE,    nullptr,      16384000);  // emb
  set(1,  d_in[3],  nullptr, cDB,        32000);     // dec_bias
  set(2,  d_in[4],  cWih,  nullptr,      1048576);   // Wih
  set(3,  d_in[5],  nullptr, cWhh,       1048576);   // Whh
  set(4,  d_in[6],  nullptr, cBih,       2048);      // bih
  set(5,  d_in[7],  nullptr, cBhh,       2048);      // bhh
  set(6,  d_in[8],  cWpih, nullptr,      40960);     // Wp_ih
  set(7,  d_in[9],  nullptr, cSmall+0,   1600);      // Wp_hh
  set(8,  d_in[10], nullptr, cSmall+1600, 80);       // bp_ih
  set(9,  d_in[11], nullptr, cSmall+1680, 80);       // bp_hh
  set(10, d_in[12], nullptr, cSmall+1760, 60);       // Wmu
  set(11, d_in[13], nullptr, cSmall+1820, 3);        // bmu
  set(12, d_in[14], nullptr, cSmall+1823, 20);       // Wsig
  set(13, d_in[15], nullptr, cSmall+1843, 1);        // bsig
  set(14, d_in[16], nullptr, cWc,        524288);    // Wc
  set(15, d_in[17], nullptr, cSmall+1844, 512);      // bc
  kC_convert<<<dim3(256,16), 256, 0, stream>>>(tab, flag);

  hipMemsetAsync(encg, 0xAA, (size_t)TT*BB*HH*4, stream);
  k1_embed_xw<<<dim3(32,16), 256, 0, stream>>>(ids, cE, cWih, cBih, cBhh, xw);
  k2_encoder<<<dim3(68), 256, 0, stream>>>(xw, cWhh, padl, cWpih, cSmall,
                                           encg, encf, mug, invg);
  k3_ctx<<<dim3(128,4), 512, 0, stream>>>(encf, mug, invg, ctx);
  k4_combined<<<dim3(512), 256, 0, stream>>>(ctx, encf, cWc, cSmall+1844, comb);
  k5_decoder<<<dim3(32,250), 256, 0, stream>>>(comb, cE, cDB, flag, d_out);
}